// Round 2
// baseline (504.974 us; speedup 1.0000x reference)
//
#include <hip/hip_runtime.h>

// Problem: x [T, B, C, H, W] = [5, 32, 128, 32, 32] fp32, LIF scan.
// R9 post-mortem: cooperative grid.sync() is the wrong tool -- rocprof shows
// lif_coop at ~890us/dispatch with VALUBusy 1.5% (pure waiting). grid.sync
// does device-scope fences (L2 wb/inv across 8 non-coherent XCDs, with 16MB
// of dirty out-writes in L2 per step) plus a 1024-block barrier, when the
// real dependence is ONE u32 per (step, channel) shared by only 8 blocks.
// R10: plain launch, register-resident state, lock-free per-channel combining
// cell: each block atomicAdds (count | 1<<28) into acc[t][c] (agent scope),
// then spin-loads until the arrival nibble hits 8. No grid barrier, no
// device-wide fence, no L2 flush. acc region (2.5KB) is zeroed by a
// hipMemsetAsync before the launch (graph-capturable). Deadlock safety:
// __launch_bounds__(256,8) pins VGPR<=64 (R9 measured 56 for this body) so
// capacity is 8 blocks/CU * 256 CU = 2048 >= 1024-block grid -> the whole
// grid is co-resident; every producer adds before any consumer spins.
// Per-element arithmetic and the ema/inhw float sequence are bit-identical
// to R8/R9 (absmax must stay exactly 0.0).
constexpr int T    = 5;
constexpr int C    = 128;
constexpr int NPT4 = 32 * C * 1024 / 4;    // f4 per timestep = 1,048,576

constexpr int SBLOCKS  = 1024;
constexpr int STHREADS = 256;
constexpr int KT       = 4;                // (b,c) tiles per block (4096/1024)

// d_ws layout (stream path): acc u32[T][C] combining cells, zeroed pre-launch.
constexpr size_t ACC_BYTES = (size_t)T * C * sizeof(unsigned int);  // 2560

// ---- R10: single plain kernel, per-channel flag sync ----
__global__ __launch_bounds__(STHREADS, 8)
void lif_stream(const float4* __restrict__ xe4,
                const float4* __restrict__ xi4,
                const float* __restrict__ alpha_raw,
                const float* __restrict__ beta_raw,
                float4* __restrict__ out4,
                unsigned int* __restrict__ acc) {
#pragma clang fp contract(off)
  const int blk = blockIdx.x;
  const int tid = threadIdx.x;
  const int c   = blk & (C - 1);           // all KT tiles of this block are channel c
  __shared__ float s_inhw;
  __shared__ unsigned int wsum[STHREADS / 64];

  const float alpha = 4.0f / (1.0f + expf(-alpha_raw[0])); // 4*sigmoid
  const float beta  = 1.0f / (1.0f + expf(-beta_raw[0]));  // sigmoid

  const size_t fi0 = (size_t)blk * 256 + tid;

  // double-buffered input regs: e/i = current step, en/ix = prefetched next
  float4 e[KT], i[KT], en[KT], ix[KT];
#pragma unroll
  for (int k = 0; k < KT; ++k) {
    const size_t fi = fi0 + (size_t)(k * SBLOCKS) * 256;
    e[k] = xe4[fi];
    i[k] = xi4[fi];
  }

  float mv[KT][4];                         // membrane state: registers, all 5 steps
#pragma unroll
  for (int k = 0; k < KT; ++k)
#pragma unroll
    for (int j = 0; j < 4; ++j) mv[k][j] = 0.0f;

  float inhw = 0.0f;                       // inh_weight starts 0
  float ema  = 0.17f;                      // EMA_INIT; only tid 0's copy is used

  for (int t = 0; t < T; ++t) {
    const size_t tb = (size_t)t * NPT4;

    // prefetch t+1 inputs BEFORE compute+reduce: independent of inhw, so the
    // loads stay in flight under the (cheap) per-channel sync.
    if (t < T - 1) {
      const size_t tb1 = tb + NPT4;
#pragma unroll
      for (int k = 0; k < KT; ++k) {
        const size_t fi = fi0 + (size_t)(k * SBLOCKS) * 256;
        en[k] = xe4[tb1 + fi];
        ix[k] = xi4[tb1 + fi];
      }
    }

    unsigned int local = 0;
#pragma unroll
    for (int k = 0; k < KT; ++k) {
      const size_t fi = fi0 + (size_t)(k * SBLOCKS) * 256;
      const float xe[4] = {e[k].x, e[k].y, e[k].z, e[k].w};
      const float xi[4] = {i[k].x, i[k].y, i[k].z, i[k].w};
      float sv[4];
#pragma unroll
      for (int j = 0; j < 4; ++j) {
        // identical arithmetic to R5/R7/R8/R9 (absmax exactly 0.0): IEEE
        // divide, literal python op order, contract off
        const float e_in = xe[j] / (1.0f + alpha * xi[j]);
        const float a  = 0.5f * mv[k][j];
        const float bb = a + e_in;
        const float d  = (beta * xi[j]) * (1.0f - inhw);
        const float m  = bb - d;
        const float x  = m - 0.5f;             // mem - V_TH
        const float s  = (x >= 0.0f) ? 1.0f : 0.0f;
        local += (x >= 0.0f) ? 1u : 0u;
        mv[k][j] = m - 0.5f * s;               // soft reset
        sv[j] = s;
      }
      float4 s4; s4.x = sv[0]; s4.y = sv[1]; s4.z = sv[2]; s4.w = sv[3];
      out4[tb + fi] = s4;
    }
    if (t == T - 1) break;                     // t=4 coupling never read

    // block reduction of spike count (4 waves)
#pragma unroll
    for (int off = 32; off > 0; off >>= 1) local += __shfl_down(local, off);
    if ((tid & 63) == 0) wsum[tid >> 6] = local;
    __syncthreads();
    if (tid == 0) {
      const unsigned int total = wsum[0] + wsum[1] + wsum[2] + wsum[3];
      // combining cell: low 28 bits = spike-count sum (max 8*4096 << 2^28),
      // high nibble = arrival count. Agent scope -> coherent across XCD L2s.
      unsigned int* cell = &acc[t * C + c];
      __hip_atomic_fetch_add(cell, total | (1u << 28),
                             __ATOMIC_RELEASE, __HIP_MEMORY_SCOPE_AGENT);
      unsigned int v = __hip_atomic_load(cell, __ATOMIC_ACQUIRE,
                                         __HIP_MEMORY_SCOPE_AGENT);
      while ((v >> 28) < 8u) {                 // '>=8' exit: replay-safe, no hang
        __builtin_amdgcn_s_sleep(2);
        v = __hip_atomic_load(cell, __ATOMIC_ACQUIRE, __HIP_MEMORY_SCOPE_AGENT);
      }
      const unsigned int tot = v & 0x0FFFFFFFu;
      // same float sequence as the R8/R9 chain, kept incrementally
      const float mean = (float)tot * (1.0f / 32768.0f);   // exact /2^15
      ema = 0.9f * ema + 0.1f * mean;
      const float s_lo = 1.0f / (1.0f + expf(-(0.17f - ema))); // sig(LOWER-ema)
      const float s_hi = 1.0f / (1.0f + expf(-(ema - 0.23f))); // sig(ema-UPPER)
      s_inhw = 4.0f * (s_lo - s_hi);
    }
    __syncthreads();
    inhw = s_inhw;

#pragma unroll
    for (int k = 0; k < KT; ++k) { e[k] = en[k]; i[k] = ix[k]; }
  }
}

// ---- fallback: R7's passing redundant-pair kernel (used only if ws too small)
constexpr int FTHREADS = 1024;
constexpr int FWAVES   = FTHREADS / 64;
constexpr int FBLOCKS  = 2 * C;
constexpr int FK       = 8;

__global__ __launch_bounds__(FTHREADS)
void lif_fallback(const float* __restrict__ xe_g, const float* __restrict__ xi_g,
                  const float* __restrict__ alpha_raw,
                  const float* __restrict__ beta_raw, float* __restrict__ out) {
#pragma clang fp contract(off)
  const int blk = blockIdx.x, c = blk & (C - 1), half = blk >> 7;
  const int tid = threadIdx.x, wave = tid >> 6, lane = tid & 63;
  __shared__ unsigned int wsum[T - 1][FWAVES];
  const float alpha = 4.0f / (1.0f + expf(-alpha_raw[0]));
  const float beta  = 1.0f / (1.0f + expf(-beta_raw[0]));
  float mem[FK][4];
#pragma unroll
  for (int k = 0; k < FK; ++k)
#pragma unroll
    for (int j = 0; j < 4; ++j) mem[k][j] = 0.0f;
  float ema = 0.17f, inhw = 0.0f;
  const float4* xe4 = (const float4*)xe_g;
  const float4* xi4 = (const float4*)xi_g;
  float4* o4 = (float4*)out;
  auto gidx = [&](int t, int k) -> size_t {
    const int b = k * (FTHREADS / 256) + (tid >> 8);
    return (size_t)t * NPT4 + (size_t)(b * C + c) * 256 + (tid & 255);
  };
  for (int t = 0; t < T; ++t) {
    float4 e4[FK], i4[FK];
#pragma unroll
    for (int k = 0; k < FK; ++k) { const size_t idx = gidx(t, k); e4[k] = xe4[idx]; i4[k] = xi4[idx]; }
    unsigned int local = 0;
#pragma unroll
    for (int k = 0; k < FK; ++k) {
      const float xe[4] = {e4[k].x, e4[k].y, e4[k].z, e4[k].w};
      const float xi[4] = {i4[k].x, i4[k].y, i4[k].z, i4[k].w};
      float sv[4];
#pragma unroll
      for (int j = 0; j < 4; ++j) {
        const float e_in = xe[j] / (1.0f + alpha * xi[j]);
        const float a = 0.5f * mem[k][j];
        const float bb = a + e_in;
        const float d = (beta * xi[j]) * (1.0f - inhw);
        const float m = bb - d;
        const float x = m - 0.5f;
        const float s = (x >= 0.0f) ? 1.0f : 0.0f;
        local += (x >= 0.0f) ? 1u : 0u;
        mem[k][j] = m - 0.5f * s;
        sv[j] = s;
      }
      if ((k >> 2) == half) {
        float4 s4; s4.x = sv[0]; s4.y = sv[1]; s4.z = sv[2]; s4.w = sv[3];
        o4[gidx(t, k)] = s4;
      }
    }
    if (t == T - 1) break;
#pragma unroll
    for (int off = 32; off > 0; off >>= 1) local += __shfl_down(local, off);
    if (lane == 0) wsum[t][wave] = local;
    __syncthreads();
    unsigned int total = 0;
#pragma unroll
    for (int w = 0; w < FWAVES; ++w) total += wsum[t][w];
    const float mean_spike = (float)total * (1.0f / 32768.0f);
    ema = 0.9f * ema + 0.1f * mean_spike;
    const float s_lo = 1.0f / (1.0f + expf(-(0.17f - ema)));
    const float s_hi = 1.0f / (1.0f + expf(-(ema - 0.23f)));
    inhw = 4.0f * (s_lo - s_hi);
  }
}

extern "C" void kernel_launch(void* const* d_in, const int* in_sizes, int n_in,
                              void* d_out, int out_size, void* d_ws, size_t ws_size,
                              hipStream_t stream) {
  const float* xe = (const float*)d_in[0];
  const float* xi = (const float*)d_in[1];
  const float* ar = (const float*)d_in[2];
  const float* br = (const float*)d_in[3];
  float* out = (float*)d_out;

  if (ws_size >= ACC_BYTES) {
    unsigned int* acc = (unsigned int*)d_ws;
    const float4* xe4 = (const float4*)xe;
    const float4* xi4 = (const float4*)xi;
    float4* out4 = (float4*)out;
    // zero the 2.5KB combining-cell region (graph-capturable memset node)
    hipMemsetAsync(d_ws, 0, ACC_BYTES, stream);
    lif_stream<<<dim3(SBLOCKS), dim3(STHREADS), 0, stream>>>(
        xe4, xi4, ar, br, out4, acc);
  } else {
    // deterministic fallback (ws_size is constant per session -> same path
    // every call, graph-capture safe)
    lif_fallback<<<dim3(FBLOCKS), dim3(FTHREADS), 0, stream>>>(xe, xi, ar, br, out);
  }
}

// Round 3
// 230.526 us; speedup vs baseline: 2.1905x; 2.1905x over previous
//
#include <hip/hip_runtime.h>

// Problem: x [T, B, C, H, W] = [5, 32, 128, 32, 32] fp32, LIF scan.
// R10 post-mortem: the per-channel combining-cell sync WORKS (no hang,
// absmax 0.0, sync cost invisible) but __launch_bounds__(256,8) capped the
// allocator at 32 VGPRs -> the 64-VGPR input double-buffer spilled to
// scratch. Counters: WRITE_SIZE 299MB (expected 84 -> ~215MB scratch
// stores), FETCH 179MB, VALUBusy 3.3%, 385us/dispatch. Scratch round-trips
// serialized the loop.
// R11: identical structure, __launch_bounds__(256,4) -> 128 VGPR/wave
// budget; the ~100-VGPR body fits with zero spill. Co-residency for the
// spin: 4 blocks/CU * 256 CU = 1024 = grid size exactly; a session-constant
// host occupancy probe gates the path (deterministic, graph-safe) and falls
// back to the proven R8 5-kernel path if capacity < grid.
// Per-element arithmetic and the ema/inhw float sequence are bit-identical
// to R8/R9/R10 (absmax must stay exactly 0.0).
constexpr int T    = 5;
constexpr int C    = 128;
constexpr int NPT4 = 32 * C * 1024 / 4;    // f4 per timestep = 1,048,576

constexpr int SBLOCKS  = 1024;
constexpr int STHREADS = 256;
constexpr int KT       = 4;                // (b,c) tiles per block (4096/1024)

// d_ws layout: [ acc u32[T][C] cells | mem float4[NPT4] (R8 path only) ]
constexpr size_t ACC_BYTES  = (size_t)T * C * sizeof(unsigned int);       // 2560
constexpr size_t PART_BYTES = (size_t)T * SBLOCKS * sizeof(unsigned int); // 20480 (R8)
constexpr size_t WS_R8      = PART_BYTES + (size_t)NPT4 * 16;             // ~16.8MB

// ---- R11: single plain kernel, per-channel flag sync, no spills ----
__global__ __launch_bounds__(STHREADS, 4)
void lif_stream(const float4* __restrict__ xe4,
                const float4* __restrict__ xi4,
                const float* __restrict__ alpha_raw,
                const float* __restrict__ beta_raw,
                float4* __restrict__ out4,
                unsigned int* __restrict__ acc) {
#pragma clang fp contract(off)
  const int blk = blockIdx.x;
  const int tid = threadIdx.x;
  const int c   = blk & (C - 1);           // all KT tiles of this block are channel c
  __shared__ float s_inhw;
  __shared__ unsigned int wsum[STHREADS / 64];

  const float alpha = 4.0f / (1.0f + expf(-alpha_raw[0])); // 4*sigmoid
  const float beta  = 1.0f / (1.0f + expf(-beta_raw[0]));  // sigmoid

  const size_t fi0 = (size_t)blk * 256 + tid;

  // double-buffered input regs: e/i = current step, en/ix = prefetched next
  float4 e[KT], i[KT], en[KT], ix[KT];
#pragma unroll
  for (int k = 0; k < KT; ++k) {
    const size_t fi = fi0 + (size_t)(k * SBLOCKS) * 256;
    e[k] = xe4[fi];
    i[k] = xi4[fi];
  }

  float mv[KT][4];                         // membrane state: registers, all 5 steps
#pragma unroll
  for (int k = 0; k < KT; ++k)
#pragma unroll
    for (int j = 0; j < 4; ++j) mv[k][j] = 0.0f;

  float inhw = 0.0f;                       // inh_weight starts 0
  float ema  = 0.17f;                      // EMA_INIT; only tid 0's copy is used

  for (int t = 0; t < T; ++t) {
    const size_t tb = (size_t)t * NPT4;

    // prefetch t+1 inputs BEFORE compute+reduce: independent of inhw, so the
    // loads stay in flight under the (cheap) per-channel sync.
    if (t < T - 1) {
      const size_t tb1 = tb + NPT4;
#pragma unroll
      for (int k = 0; k < KT; ++k) {
        const size_t fi = fi0 + (size_t)(k * SBLOCKS) * 256;
        en[k] = xe4[tb1 + fi];
        ix[k] = xi4[tb1 + fi];
      }
    }

    unsigned int local = 0;
#pragma unroll
    for (int k = 0; k < KT; ++k) {
      const size_t fi = fi0 + (size_t)(k * SBLOCKS) * 256;
      const float xe[4] = {e[k].x, e[k].y, e[k].z, e[k].w};
      const float xi[4] = {i[k].x, i[k].y, i[k].z, i[k].w};
      float sv[4];
#pragma unroll
      for (int j = 0; j < 4; ++j) {
        // identical arithmetic to R5/R7/R8/R9/R10 (absmax exactly 0.0): IEEE
        // divide, literal python op order, contract off
        const float e_in = xe[j] / (1.0f + alpha * xi[j]);
        const float a  = 0.5f * mv[k][j];
        const float bb = a + e_in;
        const float d  = (beta * xi[j]) * (1.0f - inhw);
        const float m  = bb - d;
        const float x  = m - 0.5f;             // mem - V_TH
        const float s  = (x >= 0.0f) ? 1.0f : 0.0f;
        local += (x >= 0.0f) ? 1u : 0u;
        mv[k][j] = m - 0.5f * s;               // soft reset
        sv[j] = s;
      }
      float4 s4; s4.x = sv[0]; s4.y = sv[1]; s4.z = sv[2]; s4.w = sv[3];
      out4[tb + fi] = s4;
    }
    if (t == T - 1) break;                     // t=4 coupling never read

    // block reduction of spike count (4 waves)
#pragma unroll
    for (int off = 32; off > 0; off >>= 1) local += __shfl_down(local, off);
    if ((tid & 63) == 0) wsum[tid >> 6] = local;
    __syncthreads();
    if (tid == 0) {
      const unsigned int total = wsum[0] + wsum[1] + wsum[2] + wsum[3];
      // combining cell: low 28 bits = spike-count sum (max 8*4096 << 2^28),
      // high nibble = arrival count. Agent scope -> coherent across XCD L2s.
      unsigned int* cell = &acc[t * C + c];
      __hip_atomic_fetch_add(cell, total | (1u << 28),
                             __ATOMIC_RELEASE, __HIP_MEMORY_SCOPE_AGENT);
      unsigned int v = __hip_atomic_load(cell, __ATOMIC_ACQUIRE,
                                         __HIP_MEMORY_SCOPE_AGENT);
      while ((v >> 28) < 8u) {                 // '>=8' exit: replay-safe, no hang
        __builtin_amdgcn_s_sleep(2);
        v = __hip_atomic_load(cell, __ATOMIC_ACQUIRE, __HIP_MEMORY_SCOPE_AGENT);
      }
      const unsigned int tot = v & 0x0FFFFFFFu;
      // same float sequence as the R8/R9/R10 chain, kept incrementally
      const float mean = (float)tot * (1.0f / 32768.0f);   // exact /2^15
      ema = 0.9f * ema + 0.1f * mean;
      const float s_lo = 1.0f / (1.0f + expf(-(0.17f - ema))); // sig(LOWER-ema)
      const float s_hi = 1.0f / (1.0f + expf(-(ema - 0.23f))); // sig(ema-UPPER)
      s_inhw = 4.0f * (s_lo - s_hi);
    }
    __syncthreads();
    inhw = s_inhw;

#pragma unroll
    for (int k = 0; k < KT; ++k) { e[k] = en[k]; i[k] = ix[k]; }
  }
}

// ---- R8 path: one plain kernel per timestep (deterministic fallback) ----
__global__ __launch_bounds__(STHREADS)
void lif_step(const float4* __restrict__ xe4,
              const float4* __restrict__ xi4,
              const float* __restrict__ alpha_raw,
              const float* __restrict__ beta_raw,
              float4* __restrict__ out4,
              float4* __restrict__ memb,
              unsigned int* __restrict__ partials,
              int t) {
#pragma clang fp contract(off)
  const int blk = blockIdx.x;
  const int tid = threadIdx.x;
  const int c   = blk & (C - 1);

  __shared__ float s_inhw;
  if (tid == 0) {
    float inhw = 0.0f;
    if (t > 0) {
      float ema = 0.17f;
      for (int s = 0; s < t; ++s) {
        unsigned int tot = 0;
#pragma unroll
        for (int i = 0; i < 8; ++i) tot += partials[s * SBLOCKS + c + i * C];
        const float mean = (float)tot * (1.0f / 32768.0f);
        ema = 0.9f * ema + 0.1f * mean;
      }
      const float s_lo = 1.0f / (1.0f + expf(-(0.17f - ema)));
      const float s_hi = 1.0f / (1.0f + expf(-(ema - 0.23f)));
      inhw = 4.0f * (s_lo - s_hi);
    }
    s_inhw = inhw;
  }
  __syncthreads();
  const float inhw  = s_inhw;
  const float alpha = 4.0f / (1.0f + expf(-alpha_raw[0]));
  const float beta  = 1.0f / (1.0f + expf(-beta_raw[0]));

  unsigned int local = 0;
  const size_t tb = (size_t)t * NPT4;
#pragma unroll
  for (int k = 0; k < KT; ++k) {
    const size_t fi = (size_t)(k * SBLOCKS + blk) * 256 + tid;
    const float4 e4 = xe4[tb + fi];
    const float4 i4 = xi4[tb + fi];
    float4 m4 = {0.0f, 0.0f, 0.0f, 0.0f};
    if (t > 0) m4 = memb[fi];
    const float xe[4] = {e4.x, e4.y, e4.z, e4.w};
    const float xi[4] = {i4.x, i4.y, i4.z, i4.w};
    float mv[4] = {m4.x, m4.y, m4.z, m4.w};
    float sv[4];
#pragma unroll
    for (int j = 0; j < 4; ++j) {
      const float e_in = xe[j] / (1.0f + alpha * xi[j]);
      const float a  = 0.5f * mv[j];
      const float bb = a + e_in;
      const float d  = (beta * xi[j]) * (1.0f - inhw);
      const float m  = bb - d;
      const float x  = m - 0.5f;
      const float s  = (x >= 0.0f) ? 1.0f : 0.0f;
      local += (x >= 0.0f) ? 1u : 0u;
      mv[j] = m - 0.5f * s;
      sv[j] = s;
    }
    float4 s4; s4.x = sv[0]; s4.y = sv[1]; s4.z = sv[2]; s4.w = sv[3];
    out4[tb + fi] = s4;
    if (t < T - 1) {
      float4 nm; nm.x = mv[0]; nm.y = mv[1]; nm.z = mv[2]; nm.w = mv[3];
      memb[fi] = nm;
    }
  }

  if (t < T - 1) {
#pragma unroll
    for (int off = 32; off > 0; off >>= 1) local += __shfl_down(local, off);
    __shared__ unsigned int wsum[STHREADS / 64];
    if ((tid & 63) == 0) wsum[tid >> 6] = local;
    __syncthreads();
    if (tid == 0)
      partials[t * SBLOCKS + blk] = wsum[0] + wsum[1] + wsum[2] + wsum[3];
  }
}

// ---- last-resort fallback: R7's redundant-pair kernel (tiny ws) ----
constexpr int FTHREADS = 1024;
constexpr int FWAVES   = FTHREADS / 64;
constexpr int FBLOCKS  = 2 * C;
constexpr int FK       = 8;

__global__ __launch_bounds__(FTHREADS)
void lif_fallback(const float* __restrict__ xe_g, const float* __restrict__ xi_g,
                  const float* __restrict__ alpha_raw,
                  const float* __restrict__ beta_raw, float* __restrict__ out) {
#pragma clang fp contract(off)
  const int blk = blockIdx.x, c = blk & (C - 1), half = blk >> 7;
  const int tid = threadIdx.x, wave = tid >> 6, lane = tid & 63;
  __shared__ unsigned int wsum[T - 1][FWAVES];
  const float alpha = 4.0f / (1.0f + expf(-alpha_raw[0]));
  const float beta  = 1.0f / (1.0f + expf(-beta_raw[0]));
  float mem[FK][4];
#pragma unroll
  for (int k = 0; k < FK; ++k)
#pragma unroll
    for (int j = 0; j < 4; ++j) mem[k][j] = 0.0f;
  float ema = 0.17f, inhw = 0.0f;
  const float4* xe4 = (const float4*)xe_g;
  const float4* xi4 = (const float4*)xi_g;
  float4* o4 = (float4*)out;
  auto gidx = [&](int t, int k) -> size_t {
    const int b = k * (FTHREADS / 256) + (tid >> 8);
    return (size_t)t * NPT4 + (size_t)(b * C + c) * 256 + (tid & 255);
  };
  for (int t = 0; t < T; ++t) {
    float4 e4[FK], i4[FK];
#pragma unroll
    for (int k = 0; k < FK; ++k) { const size_t idx = gidx(t, k); e4[k] = xe4[idx]; i4[k] = xi4[idx]; }
    unsigned int local = 0;
#pragma unroll
    for (int k = 0; k < FK; ++k) {
      const float xe[4] = {e4[k].x, e4[k].y, e4[k].z, e4[k].w};
      const float xi[4] = {i4[k].x, i4[k].y, i4[k].z, i4[k].w};
      float sv[4];
#pragma unroll
      for (int j = 0; j < 4; ++j) {
        const float e_in = xe[j] / (1.0f + alpha * xi[j]);
        const float a = 0.5f * mem[k][j];
        const float bb = a + e_in;
        const float d = (beta * xi[j]) * (1.0f - inhw);
        const float m = bb - d;
        const float x = m - 0.5f;
        const float s = (x >= 0.0f) ? 1.0f : 0.0f;
        local += (x >= 0.0f) ? 1u : 0u;
        mem[k][j] = m - 0.5f * s;
        sv[j] = s;
      }
      if ((k >> 2) == half) {
        float4 s4; s4.x = sv[0]; s4.y = sv[1]; s4.z = sv[2]; s4.w = sv[3];
        o4[gidx(t, k)] = s4;
      }
    }
    if (t == T - 1) break;
#pragma unroll
    for (int off = 32; off > 0; off >>= 1) local += __shfl_down(local, off);
    if (lane == 0) wsum[t][wave] = local;
    __syncthreads();
    unsigned int total = 0;
#pragma unroll
    for (int w = 0; w < FWAVES; ++w) total += wsum[t][w];
    const float mean_spike = (float)total * (1.0f / 32768.0f);
    ema = 0.9f * ema + 0.1f * mean_spike;
    const float s_lo = 1.0f / (1.0f + expf(-(0.17f - ema)));
    const float s_hi = 1.0f / (1.0f + expf(-(ema - 0.23f)));
    inhw = 4.0f * (s_lo - s_hi);
  }
}

extern "C" void kernel_launch(void* const* d_in, const int* in_sizes, int n_in,
                              void* d_out, int out_size, void* d_ws, size_t ws_size,
                              hipStream_t stream) {
  const float* xe = (const float*)d_in[0];
  const float* xi = (const float*)d_in[1];
  const float* ar = (const float*)d_in[2];
  const float* br = (const float*)d_in[3];
  float* out = (float*)d_out;
  const float4* xe4 = (const float4*)xe;
  const float4* xi4 = (const float4*)xi;
  float4* out4 = (float4*)out;

  // Session-constant co-residency probe for the spin path (host-only
  // queries, graph-capture safe, same result every call).
  static const int stream_ok = [] {
    int dev = 0;
    if (hipGetDevice(&dev) != hipSuccess) return 0;
    int nb = 0;
    if (hipOccupancyMaxActiveBlocksPerMultiprocessor(&nb, (const void*)lif_stream,
                                                     STHREADS, 0) != hipSuccess)
      return 0;
    int cus = 0;
    if (hipDeviceGetAttribute(&cus, hipDeviceAttributeMultiprocessorCount, dev) != hipSuccess)
      return 0;
    return (nb * cus >= SBLOCKS) ? 1 : 0;  // whole grid resident -> spin is safe
  }();

  if (stream_ok && ws_size >= ACC_BYTES) {
    unsigned int* acc = (unsigned int*)d_ws;
    // zero the 2.5KB combining-cell region (graph-capturable memset node)
    hipMemsetAsync(d_ws, 0, ACC_BYTES, stream);
    lif_stream<<<dim3(SBLOCKS), dim3(STHREADS), 0, stream>>>(
        xe4, xi4, ar, br, out4, acc);
  } else if (ws_size >= WS_R8) {
    unsigned int* partials = (unsigned int*)d_ws;
    float4* memb = (float4*)((char*)d_ws + PART_BYTES);
    for (int t = 0; t < T; ++t)
      lif_step<<<dim3(SBLOCKS), dim3(STHREADS), 0, stream>>>(
          xe4, xi4, ar, br, out4, memb, partials, t);
  } else {
    lif_fallback<<<dim3(FBLOCKS), dim3(FTHREADS), 0, stream>>>(xe, xi, ar, br, out);
  }
}

// Round 4
// 229.385 us; speedup vs baseline: 2.2014x; 1.0050x over previous
//
#include <hip/hip_runtime.h>

// Problem: x [T, B, C, H, W] = [5, 32, 128, 32, 32] fp32, LIF scan.
// R11 post-mortem: no spill (WRITE=82MB exact), but 330us/dispatch @
// VALUBusy 3.9% -- ~60us/step of pure sync wait. Two causes seen in the
// counters: (1) VGPR=56 proves the compiler SANK the prefetch loads past
// the spin (their only use was after it), serializing each step's 33.6MB
// of loads behind the sync; (2) the RELEASE fetch_add / ACQUIRE spin-loads
// at agent scope emit L2 writeback (buffer_wbl2) / L2 invalidate
// (buffer_inv) on gfx950 -- 1024 blocks x 4 steps of full-L2 flush = the
// grid.sync flush storm rebuilt by hand.
// R12: (a) RELAXED ordering on the combining cell. The ONLY cross-block
// data is the 28-bit count inside the atomic word itself; single-location
// atomic coherence guarantees the load that sees arrival-nibble==8 sees
// the full sum. No other memory needs ordering -> zero cache maintenance.
// (b) asm memory barrier after the prefetch loop pins the next-step loads
// above compute+spin so they fly under the sync window.
// Per-element arithmetic and the ema/inhw float sequence are bit-identical
// to R8..R11 (absmax must stay exactly 0.0).
constexpr int T    = 5;
constexpr int C    = 128;
constexpr int NPT4 = 32 * C * 1024 / 4;    // f4 per timestep = 1,048,576

constexpr int SBLOCKS  = 1024;
constexpr int STHREADS = 256;
constexpr int KT       = 4;                // (b,c) tiles per block (4096/1024)

// d_ws layout: [ acc u32[T][C] cells | mem float4[NPT4] (R8 path only) ]
constexpr size_t ACC_BYTES  = (size_t)T * C * sizeof(unsigned int);       // 2560
constexpr size_t PART_BYTES = (size_t)T * SBLOCKS * sizeof(unsigned int); // 20480 (R8)
constexpr size_t WS_R8      = PART_BYTES + (size_t)NPT4 * 16;             // ~16.8MB

// ---- R12: single plain kernel, relaxed per-channel flag sync ----
__global__ __launch_bounds__(STHREADS, 4)
void lif_stream(const float4* __restrict__ xe4,
                const float4* __restrict__ xi4,
                const float* __restrict__ alpha_raw,
                const float* __restrict__ beta_raw,
                float4* __restrict__ out4,
                unsigned int* __restrict__ acc) {
#pragma clang fp contract(off)
  const int blk = blockIdx.x;
  const int tid = threadIdx.x;
  const int c   = blk & (C - 1);           // all KT tiles of this block are channel c
  __shared__ float s_inhw;
  __shared__ unsigned int wsum[STHREADS / 64];

  const float alpha = 4.0f / (1.0f + expf(-alpha_raw[0])); // 4*sigmoid
  const float beta  = 1.0f / (1.0f + expf(-beta_raw[0]));  // sigmoid

  const size_t fi0 = (size_t)blk * 256 + tid;

  // double-buffered input regs: e/i = current step, en/ix = prefetched next
  float4 e[KT], i[KT], en[KT], ix[KT];
#pragma unroll
  for (int k = 0; k < KT; ++k) {
    const size_t fi = fi0 + (size_t)(k * SBLOCKS) * 256;
    e[k] = xe4[fi];
    i[k] = xi4[fi];
  }

  float mv[KT][4];                         // membrane state: registers, all 5 steps
#pragma unroll
  for (int k = 0; k < KT; ++k)
#pragma unroll
    for (int j = 0; j < 4; ++j) mv[k][j] = 0.0f;

  float inhw = 0.0f;                       // inh_weight starts 0
  float ema  = 0.17f;                      // EMA_INIT; only tid 0's copy is used

  for (int t = 0; t < T; ++t) {
    const size_t tb = (size_t)t * NPT4;

    // prefetch t+1 inputs; the barrier below pins the ISSUE above the
    // compute loop and the spin, so they stay in flight under both.
    if (t < T - 1) {
      const size_t tb1 = tb + NPT4;
#pragma unroll
      for (int k = 0; k < KT; ++k) {
        const size_t fi = fi0 + (size_t)(k * SBLOCKS) * 256;
        en[k] = xe4[tb1 + fi];
        ix[k] = xi4[tb1 + fi];
      }
      // compiler-level memory barrier: loads above cannot sink below (their
      // source could alias a hypothetical asm write). No instruction emitted.
      asm volatile("" ::: "memory");
    }

    unsigned int local = 0;
#pragma unroll
    for (int k = 0; k < KT; ++k) {
      const size_t fi = fi0 + (size_t)(k * SBLOCKS) * 256;
      const float xe[4] = {e[k].x, e[k].y, e[k].z, e[k].w};
      const float xi[4] = {i[k].x, i[k].y, i[k].z, i[k].w};
      float sv[4];
#pragma unroll
      for (int j = 0; j < 4; ++j) {
        // identical arithmetic to R5/R7..R11 (absmax exactly 0.0): IEEE
        // divide, literal python op order, contract off
        const float e_in = xe[j] / (1.0f + alpha * xi[j]);
        const float a  = 0.5f * mv[k][j];
        const float bb = a + e_in;
        const float d  = (beta * xi[j]) * (1.0f - inhw);
        const float m  = bb - d;
        const float x  = m - 0.5f;             // mem - V_TH
        const float s  = (x >= 0.0f) ? 1.0f : 0.0f;
        local += (x >= 0.0f) ? 1u : 0u;
        mv[k][j] = m - 0.5f * s;               // soft reset
        sv[j] = s;
      }
      float4 s4; s4.x = sv[0]; s4.y = sv[1]; s4.z = sv[2]; s4.w = sv[3];
      out4[tb + fi] = s4;
    }
    if (t == T - 1) break;                     // t=4 coupling never read

    // block reduction of spike count (4 waves)
#pragma unroll
    for (int off = 32; off > 0; off >>= 1) local += __shfl_down(local, off);
    if ((tid & 63) == 0) wsum[tid >> 6] = local;
    __syncthreads();
    if (tid == 0) {
      const unsigned int total = wsum[0] + wsum[1] + wsum[2] + wsum[3];
      // combining cell: low 28 bits = spike-count sum (max 8*4096 << 2^28),
      // high nibble = arrival count. RELAXED: the count rides inside the
      // atomic word; single-location modification-order coherence is all we
      // need. No release/acquire -> no buffer_wbl2/buffer_inv L2 flushes.
      unsigned int* cell = &acc[t * C + c];
      __hip_atomic_fetch_add(cell, total | (1u << 28),
                             __ATOMIC_RELAXED, __HIP_MEMORY_SCOPE_AGENT);
      unsigned int v = __hip_atomic_load(cell, __ATOMIC_RELAXED,
                                         __HIP_MEMORY_SCOPE_AGENT);
      while ((v >> 28) < 8u) {                 // '>=8' exit: replay-safe, no hang
        __builtin_amdgcn_s_sleep(2);
        v = __hip_atomic_load(cell, __ATOMIC_RELAXED, __HIP_MEMORY_SCOPE_AGENT);
      }
      const unsigned int tot = v & 0x0FFFFFFFu;
      // same float sequence as the R8..R11 chain, kept incrementally
      const float mean = (float)tot * (1.0f / 32768.0f);   // exact /2^15
      ema = 0.9f * ema + 0.1f * mean;
      const float s_lo = 1.0f / (1.0f + expf(-(0.17f - ema))); // sig(LOWER-ema)
      const float s_hi = 1.0f / (1.0f + expf(-(ema - 0.23f))); // sig(ema-UPPER)
      s_inhw = 4.0f * (s_lo - s_hi);
    }
    __syncthreads();
    inhw = s_inhw;

#pragma unroll
    for (int k = 0; k < KT; ++k) { e[k] = en[k]; i[k] = ix[k]; }
  }
}

// ---- R8 path: one plain kernel per timestep (deterministic fallback) ----
__global__ __launch_bounds__(STHREADS)
void lif_step(const float4* __restrict__ xe4,
              const float4* __restrict__ xi4,
              const float* __restrict__ alpha_raw,
              const float* __restrict__ beta_raw,
              float4* __restrict__ out4,
              float4* __restrict__ memb,
              unsigned int* __restrict__ partials,
              int t) {
#pragma clang fp contract(off)
  const int blk = blockIdx.x;
  const int tid = threadIdx.x;
  const int c   = blk & (C - 1);

  __shared__ float s_inhw;
  if (tid == 0) {
    float inhw = 0.0f;
    if (t > 0) {
      float ema = 0.17f;
      for (int s = 0; s < t; ++s) {
        unsigned int tot = 0;
#pragma unroll
        for (int i = 0; i < 8; ++i) tot += partials[s * SBLOCKS + c + i * C];
        const float mean = (float)tot * (1.0f / 32768.0f);
        ema = 0.9f * ema + 0.1f * mean;
      }
      const float s_lo = 1.0f / (1.0f + expf(-(0.17f - ema)));
      const float s_hi = 1.0f / (1.0f + expf(-(ema - 0.23f)));
      inhw = 4.0f * (s_lo - s_hi);
    }
    s_inhw = inhw;
  }
  __syncthreads();
  const float inhw  = s_inhw;
  const float alpha = 4.0f / (1.0f + expf(-alpha_raw[0]));
  const float beta  = 1.0f / (1.0f + expf(-beta_raw[0]));

  unsigned int local = 0;
  const size_t tb = (size_t)t * NPT4;
#pragma unroll
  for (int k = 0; k < KT; ++k) {
    const size_t fi = (size_t)(k * SBLOCKS + blk) * 256 + tid;
    const float4 e4 = xe4[tb + fi];
    const float4 i4 = xi4[tb + fi];
    float4 m4 = {0.0f, 0.0f, 0.0f, 0.0f};
    if (t > 0) m4 = memb[fi];
    const float xe[4] = {e4.x, e4.y, e4.z, e4.w};
    const float xi[4] = {i4.x, i4.y, i4.z, i4.w};
    float mv[4] = {m4.x, m4.y, m4.z, m4.w};
    float sv[4];
#pragma unroll
    for (int j = 0; j < 4; ++j) {
      const float e_in = xe[j] / (1.0f + alpha * xi[j]);
      const float a  = 0.5f * mv[j];
      const float bb = a + e_in;
      const float d  = (beta * xi[j]) * (1.0f - inhw);
      const float m  = bb - d;
      const float x  = m - 0.5f;
      const float s  = (x >= 0.0f) ? 1.0f : 0.0f;
      local += (x >= 0.0f) ? 1u : 0u;
      mv[j] = m - 0.5f * s;
      sv[j] = s;
    }
    float4 s4; s4.x = sv[0]; s4.y = sv[1]; s4.z = sv[2]; s4.w = sv[3];
    out4[tb + fi] = s4;
    if (t < T - 1) {
      float4 nm; nm.x = mv[0]; nm.y = mv[1]; nm.z = mv[2]; nm.w = mv[3];
      memb[fi] = nm;
    }
  }

  if (t < T - 1) {
#pragma unroll
    for (int off = 32; off > 0; off >>= 1) local += __shfl_down(local, off);
    __shared__ unsigned int wsum[STHREADS / 64];
    if ((tid & 63) == 0) wsum[tid >> 6] = local;
    __syncthreads();
    if (tid == 0)
      partials[t * SBLOCKS + blk] = wsum[0] + wsum[1] + wsum[2] + wsum[3];
  }
}

// ---- last-resort fallback: R7's redundant-pair kernel (tiny ws) ----
constexpr int FTHREADS = 1024;
constexpr int FWAVES   = FTHREADS / 64;
constexpr int FBLOCKS  = 2 * C;
constexpr int FK       = 8;

__global__ __launch_bounds__(FTHREADS)
void lif_fallback(const float* __restrict__ xe_g, const float* __restrict__ xi_g,
                  const float* __restrict__ alpha_raw,
                  const float* __restrict__ beta_raw, float* __restrict__ out) {
#pragma clang fp contract(off)
  const int blk = blockIdx.x, c = blk & (C - 1), half = blk >> 7;
  const int tid = threadIdx.x, wave = tid >> 6, lane = tid & 63;
  __shared__ unsigned int wsum[T - 1][FWAVES];
  const float alpha = 4.0f / (1.0f + expf(-alpha_raw[0]));
  const float beta  = 1.0f / (1.0f + expf(-beta_raw[0]));
  float mem[FK][4];
#pragma unroll
  for (int k = 0; k < FK; ++k)
#pragma unroll
    for (int j = 0; j < 4; ++j) mem[k][j] = 0.0f;
  float ema = 0.17f, inhw = 0.0f;
  const float4* xe4 = (const float4*)xe_g;
  const float4* xi4 = (const float4*)xi_g;
  float4* o4 = (float4*)out;
  auto gidx = [&](int t, int k) -> size_t {
    const int b = k * (FTHREADS / 256) + (tid >> 8);
    return (size_t)t * NPT4 + (size_t)(b * C + c) * 256 + (tid & 255);
  };
  for (int t = 0; t < T; ++t) {
    float4 e4[FK], i4[FK];
#pragma unroll
    for (int k = 0; k < FK; ++k) { const size_t idx = gidx(t, k); e4[k] = xe4[idx]; i4[k] = xi4[idx]; }
    unsigned int local = 0;
#pragma unroll
    for (int k = 0; k < FK; ++k) {
      const float xe[4] = {e4[k].x, e4[k].y, e4[k].z, e4[k].w};
      const float xi[4] = {i4[k].x, i4[k].y, i4[k].z, i4[k].w};
      float sv[4];
#pragma unroll
      for (int j = 0; j < 4; ++j) {
        const float e_in = xe[j] / (1.0f + alpha * xi[j]);
        const float a = 0.5f * mem[k][j];
        const float bb = a + e_in;
        const float d = (beta * xi[j]) * (1.0f - inhw);
        const float m = bb - d;
        const float x = m - 0.5f;
        const float s = (x >= 0.0f) ? 1.0f : 0.0f;
        local += (x >= 0.0f) ? 1u : 0u;
        mem[k][j] = m - 0.5f * s;
        sv[j] = s;
      }
      if ((k >> 2) == half) {
        float4 s4; s4.x = sv[0]; s4.y = sv[1]; s4.z = sv[2]; s4.w = sv[3];
        o4[gidx(t, k)] = s4;
      }
    }
    if (t == T - 1) break;
#pragma unroll
    for (int off = 32; off > 0; off >>= 1) local += __shfl_down(local, off);
    if (lane == 0) wsum[t][wave] = local;
    __syncthreads();
    unsigned int total = 0;
#pragma unroll
    for (int w = 0; w < FWAVES; ++w) total += wsum[t][w];
    const float mean_spike = (float)total * (1.0f / 32768.0f);
    ema = 0.9f * ema + 0.1f * mean_spike;
    const float s_lo = 1.0f / (1.0f + expf(-(0.17f - ema)));
    const float s_hi = 1.0f / (1.0f + expf(-(ema - 0.23f)));
    inhw = 4.0f * (s_lo - s_hi);
  }
}

extern "C" void kernel_launch(void* const* d_in, const int* in_sizes, int n_in,
                              void* d_out, int out_size, void* d_ws, size_t ws_size,
                              hipStream_t stream) {
  const float* xe = (const float*)d_in[0];
  const float* xi = (const float*)d_in[1];
  const float* ar = (const float*)d_in[2];
  const float* br = (const float*)d_in[3];
  float* out = (float*)d_out;
  const float4* xe4 = (const float4*)xe;
  const float4* xi4 = (const float4*)xi;
  float4* out4 = (float4*)out;

  // Session-constant co-residency probe for the spin path (host-only
  // queries, graph-capture safe, same result every call).
  static const int stream_ok = [] {
    int dev = 0;
    if (hipGetDevice(&dev) != hipSuccess) return 0;
    int nb = 0;
    if (hipOccupancyMaxActiveBlocksPerMultiprocessor(&nb, (const void*)lif_stream,
                                                     STHREADS, 0) != hipSuccess)
      return 0;
    int cus = 0;
    if (hipDeviceGetAttribute(&cus, hipDeviceAttributeMultiprocessorCount, dev) != hipSuccess)
      return 0;
    return (nb * cus >= SBLOCKS) ? 1 : 0;  // whole grid resident -> spin is safe
  }();

  if (stream_ok && ws_size >= ACC_BYTES) {
    unsigned int* acc = (unsigned int*)d_ws;
    // zero the 2.5KB combining-cell region (graph-capturable memset node)
    hipMemsetAsync(d_ws, 0, ACC_BYTES, stream);
    lif_stream<<<dim3(SBLOCKS), dim3(STHREADS), 0, stream>>>(
        xe4, xi4, ar, br, out4, acc);
  } else if (ws_size >= WS_R8) {
    unsigned int* partials = (unsigned int*)d_ws;
    float4* memb = (float4*)((char*)d_ws + PART_BYTES);
    for (int t = 0; t < T; ++t)
      lif_step<<<dim3(SBLOCKS), dim3(STHREADS), 0, stream>>>(
          xe4, xi4, ar, br, out4, memb, partials, t);
  } else {
    lif_fallback<<<dim3(FBLOCKS), dim3(FTHREADS), 0, stream>>>(xe, xi, ar, br, out);
  }
}

// Round 5
// 228.510 us; speedup vs baseline: 2.2099x; 1.0038x over previous
//
#include <hip/hip_runtime.h>

// Problem: x [T, B, C, H, W] = [5, 32, 128, 32, 32] fp32, LIF scan.
// R12 post-mortem: RELAXED combining cell killed the L2 flush storm
// (330 -> 124us/dispatch, WRITE exactly 82MB). But VGPR=52 proves the
// prefetch double-buffer is STILL not live across the spin: the
// asm-"memory" barrier pinned nothing, because the compiler can
// rematerialize a load below a barrier when no *value* dependence holds it.
// Each step remains serial: spin -> 33.6MB cold load burst -> compute
// (~25us/step observed vs ~11us pipelined estimate).
// R13: pin by DATA DEPENDENCE. After the compute loop, an
// asm volatile with "v" input operands on every prefetched component
// forces the loaded values to be materialized in VGPRs at that point --
// load issue AND completion must precede the reduce/spin and cannot sink.
// Drain overlaps compute; after the spin only register copies remain.
// Verification signals: VGPR ~100-120, WRITE_SIZE stays exactly 82048KB
// (growth = spill = revert), dispatch ~50-70us.
// Per-element arithmetic and the ema/inhw float sequence are bit-identical
// to R8..R12 (absmax must stay exactly 0.0).
constexpr int T    = 5;
constexpr int C    = 128;
constexpr int NPT4 = 32 * C * 1024 / 4;    // f4 per timestep = 1,048,576

constexpr int SBLOCKS  = 1024;
constexpr int STHREADS = 256;
constexpr int KT       = 4;                // (b,c) tiles per block (4096/1024)

// d_ws layout: [ acc u32[T][C] cells | mem float4[NPT4] (R8 path only) ]
constexpr size_t ACC_BYTES  = (size_t)T * C * sizeof(unsigned int);       // 2560
constexpr size_t PART_BYTES = (size_t)T * SBLOCKS * sizeof(unsigned int); // 20480 (R8)
constexpr size_t WS_R8      = PART_BYTES + (size_t)NPT4 * 16;             // ~16.8MB

// Force the 4 components of a float4 to be materialized in VGPRs here:
// pins the producing loads (issue + completion) above this program point.
#define PIN_F4(v) asm volatile("" :: "v"((v).x), "v"((v).y), "v"((v).z), "v"((v).w))

// ---- R13: single plain kernel, relaxed flag sync, dependence-pinned prefetch ----
__global__ __launch_bounds__(STHREADS, 4)
void lif_stream(const float4* __restrict__ xe4,
                const float4* __restrict__ xi4,
                const float* __restrict__ alpha_raw,
                const float* __restrict__ beta_raw,
                float4* __restrict__ out4,
                unsigned int* __restrict__ acc) {
#pragma clang fp contract(off)
  const int blk = blockIdx.x;
  const int tid = threadIdx.x;
  const int c   = blk & (C - 1);           // all KT tiles of this block are channel c
  __shared__ float s_inhw;
  __shared__ unsigned int wsum[STHREADS / 64];

  const float alpha = 4.0f / (1.0f + expf(-alpha_raw[0])); // 4*sigmoid
  const float beta  = 1.0f / (1.0f + expf(-beta_raw[0]));  // sigmoid

  const size_t fi0 = (size_t)blk * 256 + tid;

  // double-buffered input regs: e/i = current step, en/ix = prefetched next
  float4 e[KT], i[KT], en[KT], ix[KT];
#pragma unroll
  for (int k = 0; k < KT; ++k) {
    const size_t fi = fi0 + (size_t)(k * SBLOCKS) * 256;
    e[k] = xe4[fi];
    i[k] = xi4[fi];
  }

  float mv[KT][4];                         // membrane state: registers, all 5 steps
#pragma unroll
  for (int k = 0; k < KT; ++k)
#pragma unroll
    for (int j = 0; j < 4; ++j) mv[k][j] = 0.0f;

  float inhw = 0.0f;                       // inh_weight starts 0
  float ema  = 0.17f;                      // EMA_INIT; only tid 0's copy is used

  for (int t = 0; t < T; ++t) {
    const size_t tb = (size_t)t * NPT4;

    // prefetch t+1 inputs: issued here, drained under the compute loop,
    // pinned complete (by value dependence) before the reduce/spin below.
    if (t < T - 1) {
      const size_t tb1 = tb + NPT4;
#pragma unroll
      for (int k = 0; k < KT; ++k) {
        const size_t fi = fi0 + (size_t)(k * SBLOCKS) * 256;
        en[k] = xe4[tb1 + fi];
        ix[k] = xi4[tb1 + fi];
      }
    }

    unsigned int local = 0;
#pragma unroll
    for (int k = 0; k < KT; ++k) {
      const size_t fi = fi0 + (size_t)(k * SBLOCKS) * 256;
      const float xe[4] = {e[k].x, e[k].y, e[k].z, e[k].w};
      const float xi[4] = {i[k].x, i[k].y, i[k].z, i[k].w};
      float sv[4];
#pragma unroll
      for (int j = 0; j < 4; ++j) {
        // identical arithmetic to R5/R7..R12 (absmax exactly 0.0): IEEE
        // divide, literal python op order, contract off
        const float e_in = xe[j] / (1.0f + alpha * xi[j]);
        const float a  = 0.5f * mv[k][j];
        const float bb = a + e_in;
        const float d  = (beta * xi[j]) * (1.0f - inhw);
        const float m  = bb - d;
        const float x  = m - 0.5f;             // mem - V_TH
        const float s  = (x >= 0.0f) ? 1.0f : 0.0f;
        local += (x >= 0.0f) ? 1u : 0u;
        mv[k][j] = m - 0.5f * s;               // soft reset
        sv[j] = s;
      }
      float4 s4; s4.x = sv[0]; s4.y = sv[1]; s4.z = sv[2]; s4.w = sv[3];
      out4[tb + fi] = s4;
    }
    if (t == T - 1) break;                     // t=4 coupling never read

    // DEPENDENCE PIN: the prefetched values must be in VGPRs here -> the
    // loads issued above cannot sink below this point (i.e. past the spin).
#pragma unroll
    for (int k = 0; k < KT; ++k) { PIN_F4(en[k]); PIN_F4(ix[k]); }

    // block reduction of spike count (4 waves)
#pragma unroll
    for (int off = 32; off > 0; off >>= 1) local += __shfl_down(local, off);
    if ((tid & 63) == 0) wsum[tid >> 6] = local;
    __syncthreads();
    if (tid == 0) {
      const unsigned int total = wsum[0] + wsum[1] + wsum[2] + wsum[3];
      // combining cell: low 28 bits = spike-count sum (max 8*4096 << 2^28),
      // high nibble = arrival count. RELAXED: the count rides inside the
      // atomic word; single-location modification-order coherence is all we
      // need. No release/acquire -> no buffer_wbl2/buffer_inv L2 flushes.
      unsigned int* cell = &acc[t * C + c];
      __hip_atomic_fetch_add(cell, total | (1u << 28),
                             __ATOMIC_RELAXED, __HIP_MEMORY_SCOPE_AGENT);
      unsigned int v = __hip_atomic_load(cell, __ATOMIC_RELAXED,
                                         __HIP_MEMORY_SCOPE_AGENT);
      while ((v >> 28) < 8u) {                 // '>=8' exit: replay-safe, no hang
        __builtin_amdgcn_s_sleep(2);
        v = __hip_atomic_load(cell, __ATOMIC_RELAXED, __HIP_MEMORY_SCOPE_AGENT);
      }
      const unsigned int tot = v & 0x0FFFFFFFu;
      // same float sequence as the R8..R12 chain, kept incrementally
      const float mean = (float)tot * (1.0f / 32768.0f);   // exact /2^15
      ema = 0.9f * ema + 0.1f * mean;
      const float s_lo = 1.0f / (1.0f + expf(-(0.17f - ema))); // sig(LOWER-ema)
      const float s_hi = 1.0f / (1.0f + expf(-(ema - 0.23f))); // sig(ema-UPPER)
      s_inhw = 4.0f * (s_lo - s_hi);
    }
    __syncthreads();
    inhw = s_inhw;

#pragma unroll
    for (int k = 0; k < KT; ++k) { e[k] = en[k]; i[k] = ix[k]; }
  }
}

// ---- R8 path: one plain kernel per timestep (deterministic fallback) ----
__global__ __launch_bounds__(STHREADS)
void lif_step(const float4* __restrict__ xe4,
              const float4* __restrict__ xi4,
              const float* __restrict__ alpha_raw,
              const float* __restrict__ beta_raw,
              float4* __restrict__ out4,
              float4* __restrict__ memb,
              unsigned int* __restrict__ partials,
              int t) {
#pragma clang fp contract(off)
  const int blk = blockIdx.x;
  const int tid = threadIdx.x;
  const int c   = blk & (C - 1);

  __shared__ float s_inhw;
  if (tid == 0) {
    float inhw = 0.0f;
    if (t > 0) {
      float ema = 0.17f;
      for (int s = 0; s < t; ++s) {
        unsigned int tot = 0;
#pragma unroll
        for (int i = 0; i < 8; ++i) tot += partials[s * SBLOCKS + c + i * C];
        const float mean = (float)tot * (1.0f / 32768.0f);
        ema = 0.9f * ema + 0.1f * mean;
      }
      const float s_lo = 1.0f / (1.0f + expf(-(0.17f - ema)));
      const float s_hi = 1.0f / (1.0f + expf(-(ema - 0.23f)));
      inhw = 4.0f * (s_lo - s_hi);
    }
    s_inhw = inhw;
  }
  __syncthreads();
  const float inhw  = s_inhw;
  const float alpha = 4.0f / (1.0f + expf(-alpha_raw[0]));
  const float beta  = 1.0f / (1.0f + expf(-beta_raw[0]));

  unsigned int local = 0;
  const size_t tb = (size_t)t * NPT4;
#pragma unroll
  for (int k = 0; k < KT; ++k) {
    const size_t fi = (size_t)(k * SBLOCKS + blk) * 256 + tid;
    const float4 e4 = xe4[tb + fi];
    const float4 i4 = xi4[tb + fi];
    float4 m4 = {0.0f, 0.0f, 0.0f, 0.0f};
    if (t > 0) m4 = memb[fi];
    const float xe[4] = {e4.x, e4.y, e4.z, e4.w};
    const float xi[4] = {i4.x, i4.y, i4.z, i4.w};
    float mv[4] = {m4.x, m4.y, m4.z, m4.w};
    float sv[4];
#pragma unroll
    for (int j = 0; j < 4; ++j) {
      const float e_in = xe[j] / (1.0f + alpha * xi[j]);
      const float a  = 0.5f * mv[j];
      const float bb = a + e_in;
      const float d  = (beta * xi[j]) * (1.0f - inhw);
      const float m  = bb - d;
      const float x  = m - 0.5f;
      const float s  = (x >= 0.0f) ? 1.0f : 0.0f;
      local += (x >= 0.0f) ? 1u : 0u;
      mv[j] = m - 0.5f * s;
      sv[j] = s;
    }
    float4 s4; s4.x = sv[0]; s4.y = sv[1]; s4.z = sv[2]; s4.w = sv[3];
    out4[tb + fi] = s4;
    if (t < T - 1) {
      float4 nm; nm.x = mv[0]; nm.y = mv[1]; nm.z = mv[2]; nm.w = mv[3];
      memb[fi] = nm;
    }
  }

  if (t < T - 1) {
#pragma unroll
    for (int off = 32; off > 0; off >>= 1) local += __shfl_down(local, off);
    __shared__ unsigned int wsum[STHREADS / 64];
    if ((tid & 63) == 0) wsum[tid >> 6] = local;
    __syncthreads();
    if (tid == 0)
      partials[t * SBLOCKS + blk] = wsum[0] + wsum[1] + wsum[2] + wsum[3];
  }
}

// ---- last-resort fallback: R7's redundant-pair kernel (tiny ws) ----
constexpr int FTHREADS = 1024;
constexpr int FWAVES   = FTHREADS / 64;
constexpr int FBLOCKS  = 2 * C;
constexpr int FK       = 8;

__global__ __launch_bounds__(FTHREADS)
void lif_fallback(const float* __restrict__ xe_g, const float* __restrict__ xi_g,
                  const float* __restrict__ alpha_raw,
                  const float* __restrict__ beta_raw, float* __restrict__ out) {
#pragma clang fp contract(off)
  const int blk = blockIdx.x, c = blk & (C - 1), half = blk >> 7;
  const int tid = threadIdx.x, wave = tid >> 6, lane = tid & 63;
  __shared__ unsigned int wsum[T - 1][FWAVES];
  const float alpha = 4.0f / (1.0f + expf(-alpha_raw[0]));
  const float beta  = 1.0f / (1.0f + expf(-beta_raw[0]));
  float mem[FK][4];
#pragma unroll
  for (int k = 0; k < FK; ++k)
#pragma unroll
    for (int j = 0; j < 4; ++j) mem[k][j] = 0.0f;
  float ema = 0.17f, inhw = 0.0f;
  const float4* xe4 = (const float4*)xe_g;
  const float4* xi4 = (const float4*)xi_g;
  float4* o4 = (float4*)out;
  auto gidx = [&](int t, int k) -> size_t {
    const int b = k * (FTHREADS / 256) + (tid >> 8);
    return (size_t)t * NPT4 + (size_t)(b * C + c) * 256 + (tid & 255);
  };
  for (int t = 0; t < T; ++t) {
    float4 e4[FK], i4[FK];
#pragma unroll
    for (int k = 0; k < FK; ++k) { const size_t idx = gidx(t, k); e4[k] = xe4[idx]; i4[k] = xi4[idx]; }
    unsigned int local = 0;
#pragma unroll
    for (int k = 0; k < FK; ++k) {
      const float xe[4] = {e4[k].x, e4[k].y, e4[k].z, e4[k].w};
      const float xi[4] = {i4[k].x, i4[k].y, i4[k].z, i4[k].w};
      float sv[4];
#pragma unroll
      for (int j = 0; j < 4; ++j) {
        const float e_in = xe[j] / (1.0f + alpha * xi[j]);
        const float a = 0.5f * mem[k][j];
        const float bb = a + e_in;
        const float d = (beta * xi[j]) * (1.0f - inhw);
        const float m = bb - d;
        const float x = m - 0.5f;
        const float s = (x >= 0.0f) ? 1.0f : 0.0f;
        local += (x >= 0.0f) ? 1u : 0u;
        mem[k][j] = m - 0.5f * s;
        sv[j] = s;
      }
      if ((k >> 2) == half) {
        float4 s4; s4.x = sv[0]; s4.y = sv[1]; s4.z = sv[2]; s4.w = sv[3];
        o4[gidx(t, k)] = s4;
      }
    }
    if (t == T - 1) break;
#pragma unroll
    for (int off = 32; off > 0; off >>= 1) local += __shfl_down(local, off);
    if (lane == 0) wsum[t][wave] = local;
    __syncthreads();
    unsigned int total = 0;
#pragma unroll
    for (int w = 0; w < FWAVES; ++w) total += wsum[t][w];
    const float mean_spike = (float)total * (1.0f / 32768.0f);
    ema = 0.9f * ema + 0.1f * mean_spike;
    const float s_lo = 1.0f / (1.0f + expf(-(0.17f - ema)));
    const float s_hi = 1.0f / (1.0f + expf(-(ema - 0.23f)));
    inhw = 4.0f * (s_lo - s_hi);
  }
}

extern "C" void kernel_launch(void* const* d_in, const int* in_sizes, int n_in,
                              void* d_out, int out_size, void* d_ws, size_t ws_size,
                              hipStream_t stream) {
  const float* xe = (const float*)d_in[0];
  const float* xi = (const float*)d_in[1];
  const float* ar = (const float*)d_in[2];
  const float* br = (const float*)d_in[3];
  float* out = (float*)d_out;
  const float4* xe4 = (const float4*)xe;
  const float4* xi4 = (const float4*)xi;
  float4* out4 = (float4*)out;

  // Session-constant co-residency probe for the spin path (host-only
  // queries, graph-capture safe, same result every call).
  static const int stream_ok = [] {
    int dev = 0;
    if (hipGetDevice(&dev) != hipSuccess) return 0;
    int nb = 0;
    if (hipOccupancyMaxActiveBlocksPerMultiprocessor(&nb, (const void*)lif_stream,
                                                     STHREADS, 0) != hipSuccess)
      return 0;
    int cus = 0;
    if (hipDeviceGetAttribute(&cus, hipDeviceAttributeMultiprocessorCount, dev) != hipSuccess)
      return 0;
    return (nb * cus >= SBLOCKS) ? 1 : 0;  // whole grid resident -> spin is safe
  }();

  if (stream_ok && ws_size >= ACC_BYTES) {
    unsigned int* acc = (unsigned int*)d_ws;
    // zero the 2.5KB combining-cell region (graph-capturable memset node)
    hipMemsetAsync(d_ws, 0, ACC_BYTES, stream);
    lif_stream<<<dim3(SBLOCKS), dim3(STHREADS), 0, stream>>>(
        xe4, xi4, ar, br, out4, acc);
  } else if (ws_size >= WS_R8) {
    unsigned int* partials = (unsigned int*)d_ws;
    float4* memb = (float4*)((char*)d_ws + PART_BYTES);
    for (int t = 0; t < T; ++t)
      lif_step<<<dim3(SBLOCKS), dim3(STHREADS), 0, stream>>>(
          xe4, xi4, ar, br, out4, memb, partials, t);
  } else {
    lif_fallback<<<dim3(FBLOCKS), dim3(FTHREADS), 0, stream>>>(xe, xi, ar, br, out);
  }
}

// Round 6
// 227.875 us; speedup vs baseline: 2.2160x; 1.0028x over previous
//
#include <hip/hip_runtime.h>

// Problem: x [T, B, C, H, W] = [5, 32, 128, 32, 32] fp32, LIF scan.
// R13 post-mortem: VGPR=52 unchanged -> the dependence pin was satisfied
// the cheap way: under the 128-VGPR budget (launch_bounds(256,4)) the
// coalescer merged en->e and the scheduler ISSUED the prefetch after the
// compute loop (where e/i die), drained at the pin, then spun. All
// dependences honored, zero overlap. Serial phases merely reordered;
// 124us identical to R12.
// R14: make overlap the path of least resistance. 512 blocks x 256 thr,
// KT=8, launch_bounds(256,2) -> 256-VGPR budget. Both input buffers live
// (~200 VGPR) fit easily, so there is no pressure motive to sink the
// prefetch issue; loads drain under compute. Bonus: 4 blocks/channel
// (half the atomic chain), and a last-arriver shortcut -- fetch_add's
// return value tells the 4th block the total directly, so the straggler
// that gates each channel skips the spin entirely.
// Verification: VGPR ~190-230 (else coalescer won again), WRITE_SIZE
// stays exactly 82048KB (growth = spill = revert), dispatch ~50-75us.
// Per-element arithmetic and the ema/inhw float sequence are bit-identical
// to R8..R13 (absmax must stay exactly 0.0): integer channel totals are
// identical whether summed from 8 or 4 block-partials.
constexpr int T    = 5;
constexpr int C    = 128;
constexpr int NPT4 = 32 * C * 1024 / 4;    // f4 per timestep = 1,048,576

// ---- R14 geometry: 512 blocks, 8 tiles/thread, 4 blocks per channel ----
constexpr int SBLOCKS  = 512;
constexpr int STHREADS = 256;
constexpr int KT       = 8;                // (b,c) tiles per block (4096/512)
constexpr int PER_CH   = SBLOCKS / C;      // 4 blocks share one channel

// d_ws layout: [ acc u32[T][C] cells | mem float4[NPT4] (R8 path only) ]
constexpr size_t ACC_BYTES  = (size_t)T * C * sizeof(unsigned int);        // 2560
constexpr size_t PART_BYTES = (size_t)T * 1024 * sizeof(unsigned int);     // 20480 (R8)
constexpr size_t WS_R8      = PART_BYTES + (size_t)NPT4 * 16;              // ~16.8MB

// Force the 4 components of a float4 to be materialized in VGPRs here:
// pins the producing loads (issue + completion) above this program point.
#define PIN_F4(v) asm volatile("" :: "v"((v).x), "v"((v).y), "v"((v).z), "v"((v).w))

// ---- R14: single plain kernel, relaxed flag sync, true double-buffer ----
__global__ __launch_bounds__(STHREADS, 2)
void lif_stream(const float4* __restrict__ xe4,
                const float4* __restrict__ xi4,
                const float* __restrict__ alpha_raw,
                const float* __restrict__ beta_raw,
                float4* __restrict__ out4,
                unsigned int* __restrict__ acc) {
#pragma clang fp contract(off)
  const int blk = blockIdx.x;
  const int tid = threadIdx.x;
  const int c   = blk & (C - 1);           // all KT tiles of this block are channel c
  __shared__ float s_inhw;
  __shared__ unsigned int wsum[STHREADS / 64];

  const float alpha = 4.0f / (1.0f + expf(-alpha_raw[0])); // 4*sigmoid
  const float beta  = 1.0f / (1.0f + expf(-beta_raw[0]));  // sigmoid

  const size_t fi0 = (size_t)blk * 256 + tid;

  // double-buffered input regs: e/i = current step, en/ix = prefetched next
  float4 e[KT], i[KT], en[KT], ix[KT];
#pragma unroll
  for (int k = 0; k < KT; ++k) {
    const size_t fi = fi0 + (size_t)(k * SBLOCKS) * 256;
    e[k] = xe4[fi];
    i[k] = xi4[fi];
  }

  float mv[KT][4];                         // membrane state: registers, all 5 steps
#pragma unroll
  for (int k = 0; k < KT; ++k)
#pragma unroll
    for (int j = 0; j < 4; ++j) mv[k][j] = 0.0f;

  float inhw = 0.0f;                       // inh_weight starts 0
  float ema  = 0.17f;                      // EMA_INIT; only tid 0's copy is used

  for (int t = 0; t < T; ++t) {
    const size_t tb = (size_t)t * NPT4;

    // prefetch t+1 inputs: issued here (no register-pressure motive to sink
    // under the 256-VGPR budget), drained under the compute loop, pinned
    // complete before the reduce/spin below.
    if (t < T - 1) {
      const size_t tb1 = tb + NPT4;
#pragma unroll
      for (int k = 0; k < KT; ++k) {
        const size_t fi = fi0 + (size_t)(k * SBLOCKS) * 256;
        en[k] = xe4[tb1 + fi];
        ix[k] = xi4[tb1 + fi];
      }
    }

    unsigned int local = 0;
#pragma unroll
    for (int k = 0; k < KT; ++k) {
      const size_t fi = fi0 + (size_t)(k * SBLOCKS) * 256;
      const float xe[4] = {e[k].x, e[k].y, e[k].z, e[k].w};
      const float xi[4] = {i[k].x, i[k].y, i[k].z, i[k].w};
      float sv[4];
#pragma unroll
      for (int j = 0; j < 4; ++j) {
        // identical arithmetic to R5/R7..R13 (absmax exactly 0.0): IEEE
        // divide, literal python op order, contract off
        const float e_in = xe[j] / (1.0f + alpha * xi[j]);
        const float a  = 0.5f * mv[k][j];
        const float bb = a + e_in;
        const float d  = (beta * xi[j]) * (1.0f - inhw);
        const float m  = bb - d;
        const float x  = m - 0.5f;             // mem - V_TH
        const float s  = (x >= 0.0f) ? 1.0f : 0.0f;
        local += (x >= 0.0f) ? 1u : 0u;
        mv[k][j] = m - 0.5f * s;               // soft reset
        sv[j] = s;
      }
      float4 s4; s4.x = sv[0]; s4.y = sv[1]; s4.z = sv[2]; s4.w = sv[3];
      out4[tb + fi] = s4;
    }
    if (t == T - 1) break;                     // t=4 coupling never read

    // DEPENDENCE PIN: prefetched values must be in VGPRs here -> loads
    // cannot sink below (i.e. past the spin).
#pragma unroll
    for (int k = 0; k < KT; ++k) { PIN_F4(en[k]); PIN_F4(ix[k]); }

    // block reduction of spike count (4 waves)
#pragma unroll
    for (int off = 32; off > 0; off >>= 1) local += __shfl_down(local, off);
    if ((tid & 63) == 0) wsum[tid >> 6] = local;
    __syncthreads();
    if (tid == 0) {
      const unsigned int mine = (wsum[0] + wsum[1] + wsum[2] + wsum[3])
                                | (1u << 28);
      // combining cell: low 28 bits = spike-count sum (max 32768 << 2^28),
      // bits 28+ = arrival count. RELAXED: the count rides inside the atomic
      // word; single-location modification-order coherence suffices. No
      // release/acquire -> no buffer_wbl2/buffer_inv L2 flushes.
      unsigned int* cell = &acc[t * C + c];
      const unsigned int old =
          __hip_atomic_fetch_add(cell, mine, __ATOMIC_RELAXED,
                                 __HIP_MEMORY_SCOPE_AGENT);
      unsigned int tot;
      if ((old >> 28) == PER_CH - 1u) {
        // last arriver: total known from the returned value -- no spin.
        tot = (old + mine) & 0x0FFFFFFFu;
      } else {
        unsigned int v = __hip_atomic_load(cell, __ATOMIC_RELAXED,
                                           __HIP_MEMORY_SCOPE_AGENT);
        while ((v >> 28) < (unsigned)PER_CH) { // '>=' exit: replay-safe
          __builtin_amdgcn_s_sleep(1);
          v = __hip_atomic_load(cell, __ATOMIC_RELAXED,
                                __HIP_MEMORY_SCOPE_AGENT);
        }
        tot = v & 0x0FFFFFFFu;
      }
      // same float sequence as the R8..R13 chain, kept incrementally
      const float mean = (float)tot * (1.0f / 32768.0f);   // exact /2^15
      ema = 0.9f * ema + 0.1f * mean;
      const float s_lo = 1.0f / (1.0f + expf(-(0.17f - ema))); // sig(LOWER-ema)
      const float s_hi = 1.0f / (1.0f + expf(-(ema - 0.23f))); // sig(ema-UPPER)
      s_inhw = 4.0f * (s_lo - s_hi);
    }
    __syncthreads();
    inhw = s_inhw;

#pragma unroll
    for (int k = 0; k < KT; ++k) { e[k] = en[k]; i[k] = ix[k]; }
  }
}

// ---- R8 path: one plain kernel per timestep (deterministic fallback) ----
constexpr int RBLOCKS = 1024;
constexpr int RKT     = 4;

__global__ __launch_bounds__(STHREADS)
void lif_step(const float4* __restrict__ xe4,
              const float4* __restrict__ xi4,
              const float* __restrict__ alpha_raw,
              const float* __restrict__ beta_raw,
              float4* __restrict__ out4,
              float4* __restrict__ memb,
              unsigned int* __restrict__ partials,
              int t) {
#pragma clang fp contract(off)
  const int blk = blockIdx.x;
  const int tid = threadIdx.x;
  const int c   = blk & (C - 1);

  __shared__ float s_inhw;
  if (tid == 0) {
    float inhw = 0.0f;
    if (t > 0) {
      float ema = 0.17f;
      for (int s = 0; s < t; ++s) {
        unsigned int tot = 0;
#pragma unroll
        for (int i = 0; i < 8; ++i) tot += partials[s * RBLOCKS + c + i * C];
        const float mean = (float)tot * (1.0f / 32768.0f);
        ema = 0.9f * ema + 0.1f * mean;
      }
      const float s_lo = 1.0f / (1.0f + expf(-(0.17f - ema)));
      const float s_hi = 1.0f / (1.0f + expf(-(ema - 0.23f)));
      inhw = 4.0f * (s_lo - s_hi);
    }
    s_inhw = inhw;
  }
  __syncthreads();
  const float inhw  = s_inhw;
  const float alpha = 4.0f / (1.0f + expf(-alpha_raw[0]));
  const float beta  = 1.0f / (1.0f + expf(-beta_raw[0]));

  unsigned int local = 0;
  const size_t tb = (size_t)t * NPT4;
#pragma unroll
  for (int k = 0; k < RKT; ++k) {
    const size_t fi = (size_t)(k * RBLOCKS + blk) * 256 + tid;
    const float4 e4 = xe4[tb + fi];
    const float4 i4 = xi4[tb + fi];
    float4 m4 = {0.0f, 0.0f, 0.0f, 0.0f};
    if (t > 0) m4 = memb[fi];
    const float xe[4] = {e4.x, e4.y, e4.z, e4.w};
    const float xi[4] = {i4.x, i4.y, i4.z, i4.w};
    float mv[4] = {m4.x, m4.y, m4.z, m4.w};
    float sv[4];
#pragma unroll
    for (int j = 0; j < 4; ++j) {
      const float e_in = xe[j] / (1.0f + alpha * xi[j]);
      const float a  = 0.5f * mv[j];
      const float bb = a + e_in;
      const float d  = (beta * xi[j]) * (1.0f - inhw);
      const float m  = bb - d;
      const float x  = m - 0.5f;
      const float s  = (x >= 0.0f) ? 1.0f : 0.0f;
      local += (x >= 0.0f) ? 1u : 0u;
      mv[j] = m - 0.5f * s;
      sv[j] = s;
    }
    float4 s4; s4.x = sv[0]; s4.y = sv[1]; s4.z = sv[2]; s4.w = sv[3];
    out4[tb + fi] = s4;
    if (t < T - 1) {
      float4 nm; nm.x = mv[0]; nm.y = mv[1]; nm.z = mv[2]; nm.w = mv[3];
      memb[fi] = nm;
    }
  }

  if (t < T - 1) {
#pragma unroll
    for (int off = 32; off > 0; off >>= 1) local += __shfl_down(local, off);
    __shared__ unsigned int wsum[STHREADS / 64];
    if ((tid & 63) == 0) wsum[tid >> 6] = local;
    __syncthreads();
    if (tid == 0)
      partials[t * RBLOCKS + blk] = wsum[0] + wsum[1] + wsum[2] + wsum[3];
  }
}

// ---- last-resort fallback: R7's redundant-pair kernel (tiny ws) ----
constexpr int FTHREADS = 1024;
constexpr int FWAVES   = FTHREADS / 64;
constexpr int FBLOCKS  = 2 * C;
constexpr int FK       = 8;

__global__ __launch_bounds__(FTHREADS)
void lif_fallback(const float* __restrict__ xe_g, const float* __restrict__ xi_g,
                  const float* __restrict__ alpha_raw,
                  const float* __restrict__ beta_raw, float* __restrict__ out) {
#pragma clang fp contract(off)
  const int blk = blockIdx.x, c = blk & (C - 1), half = blk >> 7;
  const int tid = threadIdx.x, wave = tid >> 6, lane = tid & 63;
  __shared__ unsigned int wsum[T - 1][FWAVES];
  const float alpha = 4.0f / (1.0f + expf(-alpha_raw[0]));
  const float beta  = 1.0f / (1.0f + expf(-beta_raw[0]));
  float mem[FK][4];
#pragma unroll
  for (int k = 0; k < FK; ++k)
#pragma unroll
    for (int j = 0; j < 4; ++j) mem[k][j] = 0.0f;
  float ema = 0.17f, inhw = 0.0f;
  const float4* xe4 = (const float4*)xe_g;
  const float4* xi4 = (const float4*)xi_g;
  float4* o4 = (float4*)out;
  auto gidx = [&](int t, int k) -> size_t {
    const int b = k * (FTHREADS / 256) + (tid >> 8);
    return (size_t)t * NPT4 + (size_t)(b * C + c) * 256 + (tid & 255);
  };
  for (int t = 0; t < T; ++t) {
    float4 e4[FK], i4[FK];
#pragma unroll
    for (int k = 0; k < FK; ++k) { const size_t idx = gidx(t, k); e4[k] = xe4[idx]; i4[k] = xi4[idx]; }
    unsigned int local = 0;
#pragma unroll
    for (int k = 0; k < FK; ++k) {
      const float xe[4] = {e4[k].x, e4[k].y, e4[k].z, e4[k].w};
      const float xi[4] = {i4[k].x, i4[k].y, i4[k].z, i4[k].w};
      float sv[4];
#pragma unroll
      for (int j = 0; j < 4; ++j) {
        const float e_in = xe[j] / (1.0f + alpha * xi[j]);
        const float a = 0.5f * mem[k][j];
        const float bb = a + e_in;
        const float d = (beta * xi[j]) * (1.0f - inhw);
        const float m = bb - d;
        const float x = m - 0.5f;
        const float s = (x >= 0.0f) ? 1.0f : 0.0f;
        local += (x >= 0.0f) ? 1u : 0u;
        mem[k][j] = m - 0.5f * s;
        sv[j] = s;
      }
      if ((k >> 2) == half) {
        float4 s4; s4.x = sv[0]; s4.y = sv[1]; s4.z = sv[2]; s4.w = sv[3];
        o4[gidx(t, k)] = s4;
      }
    }
    if (t == T - 1) break;
#pragma unroll
    for (int off = 32; off > 0; off >>= 1) local += __shfl_down(local, off);
    if (lane == 0) wsum[t][wave] = local;
    __syncthreads();
    unsigned int total = 0;
#pragma unroll
    for (int w = 0; w < FWAVES; ++w) total += wsum[t][w];
    const float mean_spike = (float)total * (1.0f / 32768.0f);
    ema = 0.9f * ema + 0.1f * mean_spike;
    const float s_lo = 1.0f / (1.0f + expf(-(0.17f - ema)));
    const float s_hi = 1.0f / (1.0f + expf(-(ema - 0.23f)));
    inhw = 4.0f * (s_lo - s_hi);
  }
}

extern "C" void kernel_launch(void* const* d_in, const int* in_sizes, int n_in,
                              void* d_out, int out_size, void* d_ws, size_t ws_size,
                              hipStream_t stream) {
  const float* xe = (const float*)d_in[0];
  const float* xi = (const float*)d_in[1];
  const float* ar = (const float*)d_in[2];
  const float* br = (const float*)d_in[3];
  float* out = (float*)d_out;
  const float4* xe4 = (const float4*)xe;
  const float4* xi4 = (const float4*)xi;
  float4* out4 = (float4*)out;

  // Session-constant co-residency probe for the spin path (host-only
  // queries, graph-capture safe, same result every call).
  static const int stream_ok = [] {
    int dev = 0;
    if (hipGetDevice(&dev) != hipSuccess) return 0;
    int nb = 0;
    if (hipOccupancyMaxActiveBlocksPerMultiprocessor(&nb, (const void*)lif_stream,
                                                     STHREADS, 0) != hipSuccess)
      return 0;
    int cus = 0;
    if (hipDeviceGetAttribute(&cus, hipDeviceAttributeMultiprocessorCount, dev) != hipSuccess)
      return 0;
    return (nb * cus >= SBLOCKS) ? 1 : 0;  // whole grid resident -> spin is safe
  }();

  if (stream_ok && ws_size >= ACC_BYTES) {
    unsigned int* acc = (unsigned int*)d_ws;
    // zero the 2.5KB combining-cell region (graph-capturable memset node)
    hipMemsetAsync(d_ws, 0, ACC_BYTES, stream);
    lif_stream<<<dim3(SBLOCKS), dim3(STHREADS), 0, stream>>>(
        xe4, xi4, ar, br, out4, acc);
  } else if (ws_size >= WS_R8) {
    unsigned int* partials = (unsigned int*)d_ws;
    float4* memb = (float4*)((char*)d_ws + PART_BYTES);
    for (int t = 0; t < T; ++t)
      lif_step<<<dim3(RBLOCKS), dim3(STHREADS), 0, stream>>>(
          xe4, xi4, ar, br, out4, memb, partials, t);
  } else {
    lif_fallback<<<dim3(FBLOCKS), dim3(FTHREADS), 0, stream>>>(xe, xi, ar, br, out);
  }
}